// Round 5
// baseline (496.357 us; speedup 1.0000x reference)
//
#include <hip/hip_runtime.h>
#include <stdint.h>

typedef float f32x4 __attribute__((ext_vector_type(4)));
typedef __bf16 bf16x8 __attribute__((ext_vector_type(8)));
typedef unsigned short ushort4v __attribute__((ext_vector_type(4)));

#define DIM 4608
#define BK 64
#define NT 8
#define WS_L_BYTES (16 * 4 * 512 * 16)  // 512 KiB per l: 16 k-steps x [grp4][col512][8 bf16]

// Phase boundary: wait own LDS ops, raw barrier — NO vmcnt drain (prefetch stays in flight).
#define BAR()                                    \
  do {                                           \
    __builtin_amdgcn_sched_barrier(0);           \
    asm volatile("s_waitcnt lgkmcnt(0)");        \
    __builtin_amdgcn_s_barrier();                \
    __builtin_amdgcn_sched_barrier(0);           \
  } while (0)

// ---------------- prepack: W (fp32) -> ws (bf16, c folded, B-fragment order) ----------------
__global__ __launch_bounds__(256) void prepack(const float* __restrict__ W0,
                                               const float* __restrict__ W1,
                                               const float* __restrict__ W2,
                                               char* __restrict__ ws) {
  int gid = blockIdx.x * 256 + threadIdx.x;  // 3*16*4*512 = 98304 threads
  int col = gid & 511;
  int rest = gid >> 9;
  int grp = rest & 3;
  rest >>= 2;
  int t = rest & 15;
  int l = rest >> 4;
  const float* W = (l == 0) ? W0 : ((l == 1) ? W1 : W2);
  const float c = 0.044194173824159216f;  // 1/sqrt(512) path normalization
  union {
    bf16x8 v;
    uint4 u;
  } pk;
#pragma unroll
  for (int jj = 0; jj < 8; ++jj) {
    float v = W[(t * 32 + grp * 8 + jj) * 512 + col] * c;
    pk.v[jj] = (__bf16)v;
  }
  *(uint4*)(ws + (size_t)l * WS_L_BYTES + ((size_t)((t * 4 + grp) * 512 + col) << 4)) = pk.u;
}

// ---------------- fused per-l GEMM body ----------------
// Block: BZ z-samples x 128 w-cols. 8 waves; wave = 16 cols (1 ct-tile) -> acc <= 20 VGPR.
// K=512 in 8 tiles of BK=64 (2 MFMA k-steps per tile). A double-buffered in LDS; B from
// L2-resident ws into regs. Raw-barrier pipeline, counted vmcnt, 2-phase prefetch lead.
template <int D, int BZ, int OFF>
__device__ __forceinline__ void gemm_body(int c, int j, const float* __restrict__ x1,
                                          const float* __restrict__ x2,
                                          const char* __restrict__ wsl,
                                          float* __restrict__ out,
                                          char* __restrict__ smem) {
  constexpr int BM = BZ * D;             // rows (z,i) per block
  constexpr int R = BM / 16;             // 16-row tiles
  constexpr int ABYTES = BM * BK * 2;    // bf16 A tile bytes (two kk-halves of BM*64)
  constexpr int CNT = BZ * 16 * D;       // float4 loads per A tile (BK*D/4 per z-row)
  constexpr int PF = (CNT + 511) / 512;  // load slots per thread

  const int tid = threadIdx.x;
  const int z0 = c * BZ;
  const int cb = j * 128;
  const float* xbase = x1 + (size_t)z0 * DIM + OFF;

  const int lane = tid & 63;
  const int wave = tid >> 6;
  const int llo = lane & 15;
  const int lhi = lane >> 4;

  f32x4 acc[R];
#pragma unroll
  for (int rt = 0; rt < R; ++rt) acc[rt] = (f32x4){0.f, 0.f, 0.f, 0.f};

  auto load_a = [&](f32x4 (&pa)[PF], int t) {
    const float* xs = xbase + t * (BK * D);
#pragma unroll
    for (int s = 0; s < PF; ++s) {
      int idx = tid + s * 512;
      if ((CNT % 512 == 0) || idx < CNT) {
        int zl = idx / (16 * D);
        int q = idx - zl * (16 * D);
        pa[s] = *(const f32x4*)(xs + (size_t)zl * DIM + q * 4);
      }
    }
  };

  // B-fragments for tile t: the two prepacked k-steps 2t, 2t+1; wave covers cols cb+wave*16..+15
  auto load_b = [&](bf16x8 (&b)[2], int t) {
#pragma unroll
    for (int kk = 0; kk < 2; ++kk)
      b[kk] = *(const bf16x8*)(wsl + (size_t)(2 * t + kk) * 32768 +
                               ((lhi * 512 + cb + wave * 16 + llo) << 4));
  };

  auto stage_write = [&](char* buf, f32x4 (&pa)[PF]) {
#pragma unroll
    for (int s = 0; s < PF; ++s) {
      int idx = tid + s * 512;
      if ((CNT % 512 == 0) || idx < CNT) {
        int zl = idx / (16 * D);
        int q = idx - zl * (16 * D);
        if (D == 1) {
          int u0 = q * 4;  // 4 consecutive u, same kk-half, same row
          int kk = u0 >> 5;
          int ul = u0 & 31;
          union {
            ushort4v us;
            __bf16 b[4];
          } pk;
#pragma unroll
          for (int e = 0; e < 4; ++e) pk.b[e] = (__bf16)pa[s][e];
          *(ushort4v*)(buf + kk * (BM * 64) + ((ul >> 3) * BM + zl) * 16 + (ul & 7) * 2) = pk.us;
        } else {
#pragma unroll
          for (int e = 0; e < 4; ++e) {
            int cl = q * 4 + e;
            int u = cl / D;
            int i = cl - u * D;
            int kk = u >> 5;
            int ul = u & 31;
            int r = zl * D + i;
            *(__bf16*)(buf + kk * (BM * 64) + ((ul >> 3) * BM + r) * 16 + (ul & 7) * 2) =
                (__bf16)pa[s][e];
          }
        }
      }
    }
  };

  auto compute = [&](const char* buf, bf16x8 (&b)[2]) {
#pragma unroll
    for (int kk = 0; kk < 2; ++kk) {
#pragma unroll
      for (int rt = 0; rt < R; ++rt) {
        bf16x8 af = *(const bf16x8*)(buf + kk * (BM * 64) + ((lhi * BM + rt * 16 + llo) << 4));
        acc[rt] = __builtin_amdgcn_mfma_f32_16x16x32_bf16(af, b[kk], acc[rt], 0, 0, 0);
      }
    }
  };

  // ---- prologue: 2-deep prefetch; stage tile 0 ----
  f32x4 paE[PF], paO[PF];
  bf16x8 bE[2], bO[2];
  load_a(paE, 0);
  load_b(bE, 0);
  load_a(paO, 1);
  load_b(bO, 1);
  stage_write(smem, paE);  // counted vmcnt: waits only paE(0)
  load_a(paE, 2);
  BAR();

  // ---- main loop: fully unrolled, E/O register parity compile-time ----
#pragma unroll
  for (int tt = 0; tt < NT / 2; ++tt) {
    const int t = 2 * tt;
    compute(smem, bE);
    if (t + 2 < NT) load_b(bE, t + 2);
    stage_write(smem + ABYTES, paO);
    if (t + 3 < NT) load_a(paO, t + 3);
    BAR();
    compute(smem + ABYTES, bO);
    if (t + 3 < NT) load_b(bO, t + 3);
    if (t + 2 < NT) {
      stage_write(smem, paE);
      if (t + 4 < NT) load_a(paE, t + 4);
      BAR();
    }
  }

  // ---- epilogue: C/D layout col=lane&15, row=(lane>>4)*4+reg; fold x2[z] here ----
  float* obase = out + (size_t)z0 * DIM + OFF;
#pragma unroll
  for (int rt = 0; rt < R; ++rt) {
#pragma unroll
    for (int reg = 0; reg < 4; ++reg) {
      int row = rt * 16 + lhi * 4 + reg;
      int z = row / D;
      int i = row - z * D;
      float s = x2[z0 + z];
      int col = cb + wave * 16 + llo;
      obase[(size_t)z * DIM + col * D + i] = acc[rt][reg] * s;
    }
  }
}

// Fused kernel: [0,4096) -> l2, [4096,8192) -> l1, [8192,9216) -> l0.
// Per-l local id b decodes XCD-grouped: the 4 col-blocks of a z-chunk land on one XCD.
__global__ __launch_bounds__(512, 6) void gemm_fused(const float* __restrict__ x1,
                                                     const float* __restrict__ x2,
                                                     const char* __restrict__ ws,
                                                     float* __restrict__ out) {
  __shared__ __align__(16) char smem[20480];
  int bid = blockIdx.x;
  if (bid < 4096) {
    int b = bid;
    int c = (b & 7) + 8 * (b >> 5);
    int j = (b >> 3) & 3;
    gemm_body<5, 16, 2048>(c, j, x1, x2, ws + 2 * (size_t)WS_L_BYTES, out, smem);
  } else if (bid < 8192) {
    int b = bid - 4096;
    int c = (b & 7) + 8 * (b >> 5);
    int j = (b >> 3) & 3;
    gemm_body<3, 16, 512>(c, j, x1, x2, ws + (size_t)WS_L_BYTES, out, smem);
  } else {
    int b = bid - 8192;
    int c = (b & 7) + 8 * (b >> 5);
    int j = (b >> 3) & 3;
    gemm_body<1, 64, 0>(c, j, x1, x2, ws, out, smem);
  }
}

extern "C" void kernel_launch(void* const* d_in, const int* in_sizes, int n_in,
                              void* d_out, int out_size, void* d_ws, size_t ws_size,
                              hipStream_t stream) {
  const float* x1 = (const float*)d_in[0];
  const float* x2 = (const float*)d_in[1];
  const float* W0 = (const float*)d_in[2];
  const float* W1 = (const float*)d_in[3];
  const float* W2 = (const float*)d_in[4];
  float* out = (float*)d_out;
  char* ws = (char*)d_ws;

  prepack<<<384, 256, 0, stream>>>(W0, W1, W2, ws);
  gemm_fused<<<9216, 512, 0, stream>>>(x1, x2, ws, out);
}

// Round 6
// 235.207 us; speedup vs baseline: 2.1103x; 2.1103x over previous
//
#include <hip/hip_runtime.h>
#include <stdint.h>

typedef float f32x4 __attribute__((ext_vector_type(4)));
typedef __bf16 bf16x8 __attribute__((ext_vector_type(8)));

#define DIM 4608
#define BK 64
#define NT 8
#define WS_L_BYTES (16 * 4 * 512 * 16)  // 512 KiB per l: 16 k-steps x [grp4][col512][8 bf16]

// lgkm-only phase boundary: DMA/global loads stay in flight across it.
#define BARLGKM()                                \
  do {                                           \
    __builtin_amdgcn_sched_barrier(0);           \
    asm volatile("s_waitcnt lgkmcnt(0)" ::: "memory"); \
    __builtin_amdgcn_s_barrier();                \
    __builtin_amdgcn_sched_barrier(0);           \
  } while (0)

// ---------------- prepack: W (fp32) -> ws (bf16, c folded, B-fragment order) ----------------
__global__ __launch_bounds__(256) void prepack(const float* __restrict__ W0,
                                               const float* __restrict__ W1,
                                               const float* __restrict__ W2,
                                               char* __restrict__ ws) {
  int gid = blockIdx.x * 256 + threadIdx.x;  // 3*16*4*512 = 98304 threads
  int col = gid & 511;
  int rest = gid >> 9;
  int grp = rest & 3;
  rest >>= 2;
  int t = rest & 15;
  int l = rest >> 4;
  const float* W = (l == 0) ? W0 : ((l == 1) ? W1 : W2);
  const float c = 0.044194173824159216f;  // 1/sqrt(512) path normalization
  union {
    bf16x8 v;
    uint4 u;
  } pk;
#pragma unroll
  for (int jj = 0; jj < 8; ++jj) {
    float v = W[(t * 32 + grp * 8 + jj) * 512 + col] * c;
    pk.v[jj] = (__bf16)v;
  }
  *(uint4*)(ws + (size_t)l * WS_L_BYTES + ((size_t)((t * 4 + grp) * 512 + col) << 4)) = pk.u;
}

// ---------------- fused per-l GEMM body ----------------
// Block: BZ z-samples x 256 w-cols. 8 waves; wave = 32 cols. K=512 in 8 tiles of BK=64.
// Staging: global_load_lds (fp32, raw, double-buffered) -> repack (cvt+b128 frag writes,
// single frag buffer) -> MFMA. B from L2-resident ws into regs each phase.
template <int D, int BZ, int OFF>
__device__ __forceinline__ void gemm_body(int zc, int j, const float* __restrict__ x1,
                                          const float* __restrict__ x2,
                                          const char* __restrict__ wsl,
                                          float* __restrict__ out,
                                          char* __restrict__ smem) {
  constexpr int BM = BZ * D;               // output rows (z,i) per block
  constexpr int R = BM / 16;               // 16-row MFMA tiles
  constexpr int RAWB = BZ * BK * D * 4;    // raw fp32 tile bytes
  constexpr int CH = RAWB / 16;            // 16B DMA chunks per tile
  constexpr int CPR = BK * D / 4;          // 16B chunks per z-row
  constexpr int UNITS = BM * (BK / 8);     // frag 16B units per tile
  constexpr int KD = (CH + 511) / 512;     // DMA rounds
  constexpr int KU = (UNITS + 511) / 512;  // repack rounds

  char* rawbuf = smem;
  char* fragbuf = smem + 2 * RAWB;

  const int tid = threadIdx.x;
  const int z0 = zc * BZ;
  const int cb = j * 256;
  const float* xbase = x1 + (size_t)z0 * DIM + OFF;

  const int lane = tid & 63;
  const int wave = tid >> 6;
  const int llo = lane & 15;
  const int lhi = lane >> 4;

  // Per-thread DMA source bases (phase-invariant part)
  const float* gsrc[KD];
#pragma unroll
  for (int k = 0; k < KD; ++k) {
    int c = tid + k * 512;
    int rowz = c / CPR;
    int off = c - rowz * CPR;
    gsrc[k] = xbase + (size_t)rowz * DIM + off * 4;
  }

  f32x4 acc[R][2];
#pragma unroll
  for (int rt = 0; rt < R; ++rt)
#pragma unroll
    for (int ct = 0; ct < 2; ++ct) acc[rt][ct] = (f32x4){0.f, 0.f, 0.f, 0.f};

  // ---- DMA: HBM -> raw[t&1], 16B/lane, linear LDS dest ----
  auto dma = [&](int t) {
    char* ldst = rawbuf + (t & 1) * RAWB;
    const int tof = t * (BK * D);
#pragma unroll
    for (int k = 0; k < KD; ++k) {
      int c = tid + k * 512;
      if ((CH % 512 == 0) || (c < CH)) {
        __builtin_amdgcn_global_load_lds(
            (const __attribute__((address_space(1))) uint32_t*)(gsrc[k] + tof),
            (__attribute__((address_space(3))) uint32_t*)(ldst + (size_t)c * 16), 16, 0, 0);
      }
    }
  };

  // ---- repack: raw fp32 (strided) -> frag bf16 [kg][r][16B] ----
  auto repack = [&](int t) {
    const float* raw = (const float*)(rawbuf + (t & 1) * RAWB);
#pragma unroll
    for (int s = 0; s < KU; ++s) {
      int u = tid + s * 512;
      if ((UNITS % 512 == 0) || (u < UNITS)) {
        int kg = u / BM;  // 0..7
        int r = u - kg * BM;
        int z = r / D;
        int i = r - z * D;
        const float* base = raw + z * (BK * D) + (kg * 8) * D + i;
        bf16x8 v;
#pragma unroll
        for (int jj = 0; jj < 8; ++jj) v[jj] = (__bf16)base[jj * D];
        *(bf16x8*)(fragbuf + (size_t)u * 16) = v;
      }
    }
  };

  // ---- B fragments for tile t (2 k-steps x 2 col-tiles) from L2-resident ws ----
  auto load_b = [&](bf16x8 (&b)[2][2], int t) {
#pragma unroll
    for (int kk = 0; kk < 2; ++kk)
#pragma unroll
      for (int ct = 0; ct < 2; ++ct)
        b[kk][ct] = *(const bf16x8*)(wsl + ((size_t)(((2 * t + kk) * 4 + lhi) * 512 + cb +
                                                    wave * 32 + ct * 16 + llo)
                                            << 4));
  };

  auto compute = [&](bf16x8 (&b)[2][2]) {
#pragma unroll
    for (int kk = 0; kk < 2; ++kk)
#pragma unroll
      for (int rt = 0; rt < R; ++rt) {
        bf16x8 af =
            *(const bf16x8*)(fragbuf + (((kk * 4 + lhi) * BM + rt * 16 + llo) << 4));
#pragma unroll
        for (int ct = 0; ct < 2; ++ct)
          acc[rt][ct] = __builtin_amdgcn_mfma_f32_16x16x32_bf16(af, b[kk][ct], acc[rt][ct], 0, 0, 0);
      }
  };

  // ---- pipeline ----
  dma(0);
#pragma unroll 2
  for (int t = 0; t < NT; ++t) {
    __syncthreads();  // drains DMA(t) (had a full phase in flight) + makes fragbuf reusable
    if (t + 1 < NT) dma(t + 1);  // in flight across this whole phase
    bf16x8 b[2][2];
    load_b(b, t);  // L2 ~300cyc, hidden under repack (compiler-counted wait)
    repack(t);
    BARLGKM();  // frag visible to all waves; DMA(t+1) stays in flight
    compute(b);
  }

  // ---- epilogue: C/D layout col=lane&15, row=(lane>>4)*4+reg; fold x2[z] here ----
  float* obase = out + (size_t)z0 * DIM + OFF;
#pragma unroll
  for (int rt = 0; rt < R; ++rt) {
#pragma unroll
    for (int reg = 0; reg < 4; ++reg) {
      int row = rt * 16 + lhi * 4 + reg;
      int z = row / D;
      int i = row - z * D;
      float s = x2[z0 + z];
#pragma unroll
      for (int ct = 0; ct < 2; ++ct) {
        int col = cb + wave * 32 + ct * 16 + llo;
        obase[(size_t)z * DIM + col * D + i] = acc[rt][ct][reg] * s;
      }
    }
  }
}

// Fused kernel: [0,2048) -> l2, [2048,4096) -> l1, [4096,4608) -> l0.
// lb>>1 = z-chunk, lb&1 = col half (adjacent pairs share x1 tile -> L2/L3 reuse; R4-verified).
__global__ __launch_bounds__(512, 4) void gemm_fused(const float* __restrict__ x1,
                                                     const float* __restrict__ x2,
                                                     const char* __restrict__ ws,
                                                     float* __restrict__ out) {
  // LDS: max over l of 2*RAWB + FRAGB = l2: 2*20480 + 10240 = 51200
  __shared__ __align__(16) char smem[51200];
  int bid = blockIdx.x;
  if (bid < 2048) {
    gemm_body<5, 16, 2048>(bid >> 1, bid & 1, x1, x2, ws + 2 * (size_t)WS_L_BYTES, out, smem);
  } else if (bid < 4096) {
    int b = bid - 2048;
    gemm_body<3, 16, 512>(b >> 1, b & 1, x1, x2, ws + (size_t)WS_L_BYTES, out, smem);
  } else {
    int b = bid - 4096;
    gemm_body<1, 64, 0>(b >> 1, b & 1, x1, x2, ws, out, smem);
  }
}

extern "C" void kernel_launch(void* const* d_in, const int* in_sizes, int n_in,
                              void* d_out, int out_size, void* d_ws, size_t ws_size,
                              hipStream_t stream) {
  const float* x1 = (const float*)d_in[0];
  const float* x2 = (const float*)d_in[1];
  const float* W0 = (const float*)d_in[2];
  const float* W1 = (const float*)d_in[3];
  const float* W2 = (const float*)d_in[4];
  float* out = (float*)d_out;
  char* ws = (char*)d_ws;

  prepack<<<384, 256, 0, stream>>>(W0, W1, W2, ws);
  gemm_fused<<<4608, 512, 0, stream>>>(x1, x2, ws, out);
}